// Round 1
// baseline (514.350 us; speedup 1.0000x reference)
//
#include <hip/hip_runtime.h>
#include <stdint.h>

// ---------------------------------------------------------------------------
// Fused attention block: qkv proj + RoPE + flash attention + out proj.
// All matmuls in bf16 MFMA (16x16x32), fp32 accumulation.
// Workspace layout (bytes):
//   [0,16M)        xb (x as bf16)  -- reused as Og (attn out, bf16) afterwards
//   [16M,41.9M)    wqkvT : qkv_w^T bf16  [6144][2048]
//   [41.9M,50.3M)  woT   : out_w^T bf16  [2048][2048]
//   [50.3M,67.1M)  Q bf16 [B][H][N][D] (RoPE'd, pre-scaled by 1/sqrt(D))
//   [67.1M,83.9M)  K bf16 [B][H][N][D] (RoPE'd)
//   [83.9M,100.7M) VT bf16 [B][H][D][N]
// Total 96 MB.
// ---------------------------------------------------------------------------

typedef unsigned short u16;
typedef __bf16 bf16x8 __attribute__((ext_vector_type(8)));
typedef float f32x4 __attribute__((ext_vector_type(4)));

#define DI static __device__ __forceinline__

DI u16 f2b(float f) {
  union { float f; unsigned u; } v; v.f = f;
  unsigned r = v.u + 0x7FFFu + ((v.u >> 16) & 1u);   // RNE
  return (u16)(r >> 16);
}

typedef unsigned int __attribute__((address_space(1))) *gas1_t;
typedef unsigned int __attribute__((address_space(3))) *las3_t;

DI void async16(const void* g, void* l) {
  // 16B per lane, wave-uniform LDS base + lane*16 (m97 pattern)
  __builtin_amdgcn_global_load_lds((gas1_t)g, (las3_t)l, 16, 0, 0);
}

DI bf16x8 ldsv(const u16* p) { return *(const bf16x8*)p; }

// ---------------------------------------------------------------------------
__global__ void k_cvt(const float* __restrict__ in, u16* __restrict__ out, int n4) {
  int i = blockIdx.x * blockDim.x + threadIdx.x;
  if (i >= n4) return;
  float4 v = ((const float4*)in)[i];
  ushort4 o;
  o.x = f2b(v.x); o.y = f2b(v.y); o.z = f2b(v.z); o.w = f2b(v.w);
  ((ushort4*)out)[i] = o;
}

// in fp32 [R][C] -> out bf16 [C][R]
__global__ void k_tcvt(const float* __restrict__ in, u16* __restrict__ out, int R, int C) {
  __shared__ float t[32][33];
  int bx = blockIdx.x * 32, by = blockIdx.y * 32;
  int tx = threadIdx.x, ty = threadIdx.y;
#pragma unroll
  for (int i = 0; i < 4; i++)
    t[ty + i * 8][tx] = in[(size_t)(by + ty + i * 8) * C + bx + tx];
  __syncthreads();
#pragma unroll
  for (int i = 0; i < 4; i++)
    out[(size_t)(bx + ty + i * 8) * R + by + tx] = f2b(t[tx][ty + i * 8]);
}

// ---------------------------------------------------------------------------
// 128x128 tile GEMM, BK=32, 4 waves (each 64x64), B^T input.
// MODE 0: C fp32 store.  MODE 1: fused RoPE epilogue -> Q/K/VT bf16 scatter.
template <int MODE>
__global__ __launch_bounds__(256) void k_gemm(
    const u16* __restrict__ A, const u16* __restrict__ BT, const int K,
    float* __restrict__ C, const int ldc,
    const float* __restrict__ rope,
    u16* __restrict__ Qp, u16* __restrict__ Kp, u16* __restrict__ VTp) {
  __shared__ u16 As[4096];   // [128][32] bf16, 2-way chunk-swizzled
  __shared__ u16 Bs[4096];
  const int tid = threadIdx.x;
  const int w = tid >> 6, lane = tid & 63;
  const int g = lane >> 4, lr = lane & 15;
  const int wm = (w >> 1) << 6, wn = (w & 1) << 6;
  const int bm0 = blockIdx.y << 7, bn0 = blockIdx.x << 7;

  // staging source swizzle: LDS slot (r, c') holds global 16B-chunk c' ^ ((r>>1)&3)
  const int cg = (lane & 3) ^ ((lane >> 3) & 3);
  const int l4 = lane >> 2;
  const int gsw = g ^ ((lr >> 1) & 3);   // read-side inverse

  const u16* Ag = A + (size_t)(bm0 + (w << 5) + l4) * K + (cg << 3);
  const u16* Bg = BT + (size_t)(bn0 + (w << 5) + l4) * K + (cg << 3);
  u16* Asd = As + (w << 10);
  u16* Bsd = Bs + (w << 10);
  const size_t rstep = (size_t)K << 4;  // +16 rows

  const f32x4 zf = {0.f, 0.f, 0.f, 0.f};
  f32x4 acc[4][4];
#pragma unroll
  for (int i = 0; i < 4; i++)
#pragma unroll
    for (int j = 0; j < 4; j++) acc[i][j] = zf;

  for (int kt = 0; kt < K; kt += 32) {
    async16(Ag + kt, Asd);
    async16(Ag + rstep + kt, Asd + 512);
    async16(Bg + kt, Bsd);
    async16(Bg + rstep + kt, Bsd + 512);
    __syncthreads();
    bf16x8 af[4], bf[4];
#pragma unroll
    for (int i = 0; i < 4; i++) {
      af[i] = ldsv(As + ((wm + (i << 4) + lr) << 5) + (gsw << 3));
      bf[i] = ldsv(Bs + ((wn + (i << 4) + lr) << 5) + (gsw << 3));
    }
#pragma unroll
    for (int i = 0; i < 4; i++)
#pragma unroll
      for (int j = 0; j < 4; j++)
        acc[i][j] = __builtin_amdgcn_mfma_f32_16x16x32_bf16(af[i], bf[j], acc[i][j], 0, 0, 0);
    __syncthreads();
  }

  if constexpr (MODE == 0) {
#pragma unroll
    for (int i = 0; i < 4; i++) {
      const int row0 = bm0 + wm + (i << 4) + (g << 2);
#pragma unroll
      for (int j = 0; j < 4; j++) {
        const int col = bn0 + wn + (j << 4) + lr;
#pragma unroll
        for (int e = 0; e < 4; e++)
          C[(size_t)(row0 + e) * ldc + col] = acc[i][j][e];
      }
    }
  } else {
    // column tile is 128-wide and 128-aligned -> single (s,h) per block
    const int sidx = bn0 >> 11;          // 0:q 1:k 2:v
    const int h = (bn0 >> 7) & 15;
    const int b = bm0 >> 11;
    const int nb = (bm0 & 2047) + wm;
    if (sidx < 2) {
      u16* dst = (sidx == 0 ? Qp : Kp) + ((size_t)(b * 16 + h) << 18);
      const float qs = (sidx == 0) ? 0.08838834764831845f : 1.0f;  // 1/sqrt(128)
#pragma unroll
      for (int i = 0; i < 4; i++) {
#pragma unroll
        for (int j = 0; j < 4; j++) {
          const int d = wn + (j << 4) + lr;
          const float sg = (d & 1) ? 1.f : -1.f;
          const int dpe = d & ~1, dpo = d | 1;
#pragma unroll
          for (int e = 0; e < 4; e++) {
            const int n = nb + (i << 4) + (g << 2) + e;
            const float v = acc[i][j][e];
            const float p = __shfl_xor(v, 1);    // partner column d^1
            const float cf = rope[(n << 7) + dpe];
            const float sf = rope[(n << 7) + dpo];
            dst[((size_t)n << 7) + d] = f2b((v * cf + sg * p * sf) * qs);
          }
        }
      }
    } else {
      u16* dst = VTp + ((size_t)(b * 16 + h) << 18);  // [D][N]
#pragma unroll
      for (int i = 0; i < 4; i++) {
#pragma unroll
        for (int j = 0; j < 4; j++) {
          const int d = wn + (j << 4) + lr;
          const int n0 = nb + (i << 4) + (g << 2);
          ushort4 o;
          o.x = f2b(acc[i][j][0]); o.y = f2b(acc[i][j][1]);
          o.z = f2b(acc[i][j][2]); o.w = f2b(acc[i][j][3]);
          *(ushort4*)(dst + ((size_t)d << 11) + n0) = o;
        }
      }
    }
  }
}

// ---------------------------------------------------------------------------
// Flash attention: block = 128 q-rows (4 waves x 32), loop over 16 kv-tiles of 128.
// K and V time-share one 32KB LDS buffer; P per-wave 8KB. XOR-swizzled layouts.
__global__ __launch_bounds__(256) void k_attn(
    const u16* __restrict__ Q, const u16* __restrict__ Kt,
    const u16* __restrict__ VT, u16* __restrict__ Og) {
  __shared__ u16 KV[16384];     // [128][128] bf16, swizzled: chunk ^= (row&7)
  __shared__ u16 Pb[4][4096];   // per-wave P [32][128]
  const int tid = threadIdx.x;
  const int w = tid >> 6, lane = tid & 63;
  const int g = lane >> 4, lr = lane & 15;
  const int qt = blockIdx.x, h = blockIdx.y, b = blockIdx.z;
  const size_t bh = (size_t)(b * 16 + h) << 18;
  const u16* Qb = Q + bh;
  const u16* Kb = Kt + bh;
  const u16* Vb = VT + bh;
  u16* Pw = &Pb[w][0];

  const int qr0 = (qt << 7) + (w << 5);
  bf16x8 qf[2][4];
#pragma unroll
  for (int mi = 0; mi < 2; mi++)
#pragma unroll
    for (int kk = 0; kk < 4; kk++)
      qf[mi][kk] = *(const bf16x8*)(Qb + ((size_t)(qr0 + (mi << 4) + lr) << 7) + (kk << 5) + (g << 3));

  const f32x4 zf = {0.f, 0.f, 0.f, 0.f};
  f32x4 o[2][8];
  float m_[2][4], l_[2][4];
#pragma unroll
  for (int mi = 0; mi < 2; mi++) {
#pragma unroll
    for (int ni = 0; ni < 8; ni++) o[mi][ni] = zf;
#pragma unroll
    for (int e = 0; e < 4; e++) { m_[mi][e] = -3.0e38f; l_[mi][e] = 0.f; }
  }

  for (int kt = 0; kt < 16; kt++) {
    // ---- stage K tile ----
#pragma unroll
    for (int q = 0; q < 8; q++) {
      const int r = (((w << 3) + q) << 2) + g;
      const int cc = lr ^ (((q << 2) + g) & 7);
      async16(Kb + ((size_t)((kt << 7) + r) << 7) + (cc << 3), KV + (((w << 3) + q) << 9));
    }
    __syncthreads();
    // ---- S = Q K^T ----
    f32x4 s[2][8];
#pragma unroll
    for (int mi = 0; mi < 2; mi++)
#pragma unroll
      for (int ni = 0; ni < 8; ni++) s[mi][ni] = zf;
#pragma unroll
    for (int kk = 0; kk < 4; kk++) {
      bf16x8 kf[8];
#pragma unroll
      for (int ni = 0; ni < 8; ni++) {
        const int row = (ni << 4) + lr;
        kf[ni] = ldsv(KV + (row << 7) + ((((kk << 2) + g) ^ (row & 7)) << 3));
      }
#pragma unroll
      for (int mi = 0; mi < 2; mi++)
#pragma unroll
        for (int ni = 0; ni < 8; ni++)
          s[mi][ni] = __builtin_amdgcn_mfma_f32_16x16x32_bf16(qf[mi][kk], kf[ni], s[mi][ni], 0, 0, 0);
    }
    __syncthreads();  // all K reads done before V overwrites buffer
    // ---- stage V tile (issue now, waited at next barrier; softmax hides latency)
#pragma unroll
    for (int q = 0; q < 8; q++) {
      const int r = (((w << 3) + q) << 2) + g;   // d index
      const int cc = lr ^ (((q << 2) + g) & 7);
      async16(Vb + ((size_t)r << 11) + (kt << 7) + (cc << 3), KV + (((w << 3) + q) << 9));
    }
    // ---- online softmax (VALU only) ----
#pragma unroll
    for (int mi = 0; mi < 2; mi++) {
      float mx[4], al[4], ps[4];
#pragma unroll
      for (int e = 0; e < 4; e++) {
        float v = s[mi][0][e];
#pragma unroll
        for (int ni = 1; ni < 8; ni++) v = fmaxf(v, s[mi][ni][e]);
        v = fmaxf(v, __shfl_xor(v, 1));
        v = fmaxf(v, __shfl_xor(v, 2));
        v = fmaxf(v, __shfl_xor(v, 4));
        v = fmaxf(v, __shfl_xor(v, 8));
        mx[e] = fmaxf(v, m_[mi][e]);
        al[e] = __expf(m_[mi][e] - mx[e]);
        m_[mi][e] = mx[e];
        ps[e] = 0.f;
      }
#pragma unroll
      for (int ni = 0; ni < 8; ni++)
#pragma unroll
        for (int e = 0; e < 4; e++) {
          const float p = __expf(s[mi][ni][e] - mx[e]);
          s[mi][ni][e] = p;
          ps[e] += p;
        }
#pragma unroll
      for (int e = 0; e < 4; e++) {
        ps[e] += __shfl_xor(ps[e], 1);
        ps[e] += __shfl_xor(ps[e], 2);
        ps[e] += __shfl_xor(ps[e], 4);
        ps[e] += __shfl_xor(ps[e], 8);
        l_[mi][e] = l_[mi][e] * al[e] + ps[e];
      }
#pragma unroll
      for (int ni = 0; ni < 8; ni++)
#pragma unroll
        for (int e = 0; e < 4; e++) o[mi][ni][e] *= al[e];
      // P -> LDS bf16 (swizzled rows)
#pragma unroll
      for (int ni = 0; ni < 8; ni++)
#pragma unroll
        for (int e = 0; e < 4; e++) {
          const int row = (mi << 4) + (g << 2) + e;
          const int col = (ni << 4) + lr;
          Pw[(row << 7) + (((col >> 3) ^ (row & 7)) << 3) + (col & 7)] = f2b(s[mi][ni][e]);
        }
    }
    __syncthreads();  // V staged + P visible
    // ---- O += P V ----
#pragma unroll
    for (int kk = 0; kk < 4; kk++) {
      bf16x8 pf[2];
#pragma unroll
      for (int mi = 0; mi < 2; mi++) {
        const int row = (mi << 4) + lr;
        pf[mi] = ldsv(Pw + (row << 7) + ((((kk << 2) + g) ^ (row & 7)) << 3));
      }
      bf16x8 vf[8];
#pragma unroll
      for (int ni = 0; ni < 8; ni++) {
        const int d = (ni << 4) + lr;
        vf[ni] = ldsv(KV + (d << 7) + ((((kk << 2) + g) ^ (d & 7)) << 3));
      }
#pragma unroll
      for (int mi = 0; mi < 2; mi++)
#pragma unroll
        for (int ni = 0; ni < 8; ni++)
          o[mi][ni] = __builtin_amdgcn_mfma_f32_16x16x32_bf16(pf[mi], vf[ni], o[mi][ni], 0, 0, 0);
    }
    __syncthreads();  // V reads done before next K stage
  }
  // ---- epilogue: O/l -> Og bf16 [B*N][2048]
  u16* Ob = Og + ((size_t)b << 22) + (h << 7);
#pragma unroll
  for (int mi = 0; mi < 2; mi++) {
    float inv[4];
#pragma unroll
    for (int e = 0; e < 4; e++) inv[e] = 1.0f / l_[mi][e];
#pragma unroll
    for (int ni = 0; ni < 8; ni++) {
      const int d = (ni << 4) + lr;
#pragma unroll
      for (int e = 0; e < 4; e++) {
        const int n = qr0 + (mi << 4) + (g << 2) + e;
        Ob[((size_t)n << 11) + d] = f2b(o[mi][ni][e] * inv[e]);
      }
    }
  }
}

// ---------------------------------------------------------------------------
extern "C" void kernel_launch(void* const* d_in, const int* in_sizes, int n_in,
                              void* d_out, int out_size, void* d_ws, size_t ws_size,
                              hipStream_t stream) {
  const float* x = (const float*)d_in[0];
  const float* rope = (const float*)d_in[1];
  const float* qkv_w = (const float*)d_in[2];
  const float* out_w = (const float*)d_in[3];
  float* out = (float*)d_out;

  char* ws = (char*)d_ws;
  u16* xb    = (u16*)(ws);                 // 16,777,216 B ; reused as Og
  u16* wqkvT = (u16*)(ws + 16777216);      // 25,165,824 B
  u16* woT   = (u16*)(ws + 41943040);      //  8,388,608 B
  u16* Qp    = (u16*)(ws + 50331648);      // 16,777,216 B
  u16* Kp    = (u16*)(ws + 67108864);      // 16,777,216 B
  u16* VTp   = (u16*)(ws + 83886080);      // 16,777,216 B
  u16* Og    = xb;                          // alias: xb dead after gemm1

  // x (2*2048*2048 fp32) -> bf16
  k_cvt<<<8192, 256, 0, stream>>>(x, xb, 2097152);
  // qkv_w [2048][6144] -> [6144][2048] bf16 ; out_w [2048][2048] -> T bf16
  k_tcvt<<<dim3(192, 64), dim3(32, 8), 0, stream>>>(qkv_w, wqkvT, 2048, 6144);
  k_tcvt<<<dim3(64, 64), dim3(32, 8), 0, stream>>>(out_w, woT, 2048, 2048);
  // qkv projection + RoPE + scatter to Q/K/VT
  k_gemm<1><<<dim3(48, 32), 256, 0, stream>>>(xb, wqkvT, 2048, nullptr, 0, rope, Qp, Kp, VTp);
  // flash attention
  k_attn<<<dim3(16, 16, 2), 256, 0, stream>>>(Qp, Kp, VTp, Og);
  // output projection -> fp32 d_out
  k_gemm<0><<<dim3(16, 32), 256, 0, stream>>>(Og, woT, 2048, out, 2048, nullptr, nullptr, nullptr, nullptr);
}

// Round 7
// 442.036 us; speedup vs baseline: 1.1636x; 1.1636x over previous
//
#include <hip/hip_runtime.h>
#include <stdint.h>

// ---------------------------------------------------------------------------
// Fused attention block: qkv proj + RoPE + flash attention + out proj.
// All matmuls in bf16 MFMA (16x16x32), fp32 accumulation.
// Workspace layout (bytes):
//   [0,16M)        xb (x as bf16)  -- reused as Og (attn out, bf16) afterwards
//   [16M,41.9M)    wqkvT : qkv_w^T bf16  [6144][2048]
//   [41.9M,50.3M)  woT   : out_w^T bf16  [2048][2048]
//   [50.3M,67.1M)  Q bf16 [B][H][N][D] (RoPE'd, pre-scaled by log2(e)/sqrt(D))
//   [67.1M,83.9M)  K bf16 [B][H][N][D] (RoPE'd)
//   [83.9M,100.7M) VT bf16 [B][H][D][N]
// Total 96 MB.
// ---------------------------------------------------------------------------

typedef unsigned short u16;
typedef __bf16 bf16x8 __attribute__((ext_vector_type(8)));
typedef float f32x4 __attribute__((ext_vector_type(4)));

#define DI static __device__ __forceinline__

DI u16 f2b(float f) {
  union { float f; unsigned u; } v; v.f = f;
  unsigned r = v.u + 0x7FFFu + ((v.u >> 16) & 1u);   // RNE
  return (u16)(r >> 16);
}

#if __has_builtin(__builtin_amdgcn_exp2f)
DI float EXP2(float x) { return __builtin_amdgcn_exp2f(x); }
#else
DI float EXP2(float x) { return exp2f(x); }
#endif

typedef unsigned int __attribute__((address_space(1))) *gas1_t;
typedef unsigned int __attribute__((address_space(3))) *las3_t;

DI void async16(const void* g, void* l) {
  // 16B per lane, wave-uniform LDS base + lane*16 (m97 pattern)
  __builtin_amdgcn_global_load_lds((gas1_t)g, (las3_t)l, 16, 0, 0);
}

DI bf16x8 ldsv(const u16* p) { return *(const bf16x8*)p; }

// ---------------------------------------------------------------------------
__global__ void k_cvt(const float* __restrict__ in, u16* __restrict__ out, int n4) {
  int i = blockIdx.x * blockDim.x + threadIdx.x;
  if (i >= n4) return;
  float4 v = ((const float4*)in)[i];
  ushort4 o;
  o.x = f2b(v.x); o.y = f2b(v.y); o.z = f2b(v.z); o.w = f2b(v.w);
  ((ushort4*)out)[i] = o;
}

// in fp32 [R][C] -> out bf16 [C][R]
__global__ void k_tcvt(const float* __restrict__ in, u16* __restrict__ out, int R, int C) {
  __shared__ float t[32][33];
  int bx = blockIdx.x * 32, by = blockIdx.y * 32;
  int tx = threadIdx.x, ty = threadIdx.y;
#pragma unroll
  for (int i = 0; i < 4; i++)
    t[ty + i * 8][tx] = in[(size_t)(by + ty + i * 8) * C + bx + tx];
  __syncthreads();
#pragma unroll
  for (int i = 0; i < 4; i++)
    out[(size_t)(bx + ty + i * 8) * R + by + tx] = f2b(t[tx][ty + i * 8]);
}

// ---------------------------------------------------------------------------
// 128x128 tile GEMM, BK=64 (m97 config), 4 waves (each 64x64), B^T input.
// LDS [128][64] bf16 per operand (16KB x2), 16B-chunk swizzle: slot (row,c')
// holds global chunk c' ^ (row&7)  (pre-swizzled source, linear LDS dest).
// MODE 0: C fp32 store.  MODE 1: fused RoPE epilogue -> Q/K/VT bf16 scatter.
template <int MODE>
__global__ __launch_bounds__(256) void k_gemm(
    const u16* __restrict__ A, const u16* __restrict__ BT, const int K,
    float* __restrict__ C, const int ldc,
    const float* __restrict__ rope,
    u16* __restrict__ Qp, u16* __restrict__ Kp, u16* __restrict__ VTp) {
  __shared__ u16 As[8192];   // [128][64]
  __shared__ u16 Bs[8192];
  const int tid = threadIdx.x;
  const int w = tid >> 6, lane = tid & 63;
  const int g = lane >> 4, lr = lane & 15;
  const int wm = (w >> 1) << 6, wn = (w & 1) << 6;
  const int bm0 = blockIdx.y << 7, bn0 = blockIdx.x << 7;

  // staging: lane l of call i writes LDS row (w*32 + i*8 + (l>>3)), chunk l&7.
  // source chunk = (l&7) ^ (l>>3)  so that slot (row,c') = global c' ^ (row&7).
  const int cg8 = (lane & 7) ^ (lane >> 3);
  const int row_l = lane >> 3;             // 0..7

  const u16* Ag = A + (size_t)(bm0 + (w << 5) + row_l) * K + (cg8 << 3);
  const u16* Bg = BT + (size_t)(bn0 + (w << 5) + row_l) * K + (cg8 << 3);
  u16* Asd = As + (w << 11);
  u16* Bsd = Bs + (w << 11);
  const size_t rstep = (size_t)K << 3;  // +8 rows

  const f32x4 zf = {0.f, 0.f, 0.f, 0.f};
  f32x4 acc[4][4];
#pragma unroll
  for (int i = 0; i < 4; i++)
#pragma unroll
    for (int j = 0; j < 4; j++) acc[i][j] = zf;

  for (int kt = 0; kt < K; kt += 64) {
#pragma unroll
    for (int i = 0; i < 4; i++) {
      async16(Ag + (size_t)i * rstep + kt, Asd + (i << 9));
      async16(Bg + (size_t)i * rstep + kt, Bsd + (i << 9));
    }
    __syncthreads();
#pragma unroll
    for (int kk = 0; kk < 2; kk++) {
      bf16x8 af[4], bf[4];
      const int swz = ((((kk << 2) + g) ^ (lr & 7)) << 3);
#pragma unroll
      for (int i = 0; i < 4; i++) {
        af[i] = ldsv(As + ((wm + (i << 4) + lr) << 6) + swz);
        bf[i] = ldsv(Bs + ((wn + (i << 4) + lr) << 6) + swz);
      }
#pragma unroll
      for (int i = 0; i < 4; i++)
#pragma unroll
        for (int j = 0; j < 4; j++)
          acc[i][j] = __builtin_amdgcn_mfma_f32_16x16x32_bf16(af[i], bf[j], acc[i][j], 0, 0, 0);
    }
    __syncthreads();
  }

  if constexpr (MODE == 0) {
#pragma unroll
    for (int i = 0; i < 4; i++) {
      const int row0 = bm0 + wm + (i << 4) + (g << 2);
#pragma unroll
      for (int j = 0; j < 4; j++) {
        const int col = bn0 + wn + (j << 4) + lr;
#pragma unroll
        for (int e = 0; e < 4; e++)
          C[(size_t)(row0 + e) * ldc + col] = acc[i][j][e];
      }
    }
  } else {
    // column tile is 128-wide and 128-aligned -> single (s,h) per block
    const int sidx = bn0 >> 11;          // 0:q 1:k 2:v
    const int h = (bn0 >> 7) & 15;
    const int b = bm0 >> 11;
    const int nb = (bm0 & 2047) + wm;
    if (sidx < 2) {
      u16* dst = (sidx == 0 ? Qp : Kp) + ((size_t)(b * 16 + h) << 18);
      // Q gets 1/sqrt(128) * log2(e) so softmax can use exp2 directly.
      const float qs = (sidx == 0) ? 0.08838834764831845f * 1.4426950408889634f : 1.0f;
#pragma unroll
      for (int i = 0; i < 4; i++) {
#pragma unroll
        for (int j = 0; j < 4; j++) {
          const int d = wn + (j << 4) + lr;
          const float sg = (d & 1) ? 1.f : -1.f;
          const int dpe = d & ~1, dpo = d | 1;
#pragma unroll
          for (int e = 0; e < 4; e++) {
            const int n = nb + (i << 4) + (g << 2) + e;
            const float v = acc[i][j][e];
            const float p = __shfl_xor(v, 1);    // partner column d^1
            const float cf = rope[(n << 7) + dpe];
            const float sf = rope[(n << 7) + dpo];
            dst[((size_t)n << 7) + d] = f2b((v * cf + sg * p * sf) * qs);
          }
        }
      }
    } else {
      u16* dst = VTp + ((size_t)(b * 16 + h) << 18);  // [D][N]
#pragma unroll
      for (int i = 0; i < 4; i++) {
#pragma unroll
        for (int j = 0; j < 4; j++) {
          const int d = wn + (j << 4) + lr;
          const int n0 = nb + (i << 4) + (g << 2);
          ushort4 o;
          o.x = f2b(acc[i][j][0]); o.y = f2b(acc[i][j][1]);
          o.z = f2b(acc[i][j][2]); o.w = f2b(acc[i][j][3]);
          *(ushort4*)(dst + ((size_t)d << 11) + n0) = o;
        }
      }
    }
  }
}

// ---------------------------------------------------------------------------
// Flash attention v2: 512 blocks (16 q-tiles x 16 heads x 2 batch), 4 waves x 32 q.
// XCD-aware swizzle: hardware block bid -> logical wgid = (bid%8)*64 + bid/8,
// so each XCD's 64 blocks = 4 complete (b,h) groups -> 4MB K/V per L2 (fits).
// Separate K (16KB) and V (16KB) LDS buffers + per-wave P (4KB) -> 48KB.
// 2 barriers/tile; stageK hides under PV, stageV hides under QK^T+softmax.
// Scores arrive pre-scaled by log2(e) -> exp2-based online softmax + defer-max.
// T5: s_setprio(1) around both MFMA clusters.
__global__ __launch_bounds__(256, 2) void k_attn(
    const u16* __restrict__ Q, const u16* __restrict__ Kt,
    const u16* __restrict__ VT, u16* __restrict__ Og) {
  __shared__ u16 Ks[8192];      // [64 n][128 d], 16B-chunk ^= (row&7)
  __shared__ u16 Vs[8192];      // [128 d][64 n], 16B-chunk ^= (d&7)
  __shared__ u16 Pb[4][2048];   // per-wave [32 q][64 n], chunk ^= (row&7)
  const int tid = threadIdx.x;
  const int w = tid >> 6, lane = tid & 63;
  const int g = lane >> 4, lr = lane & 15;
  // XCD swizzle (bijective: 512 = 8 * 64)
  const int wgid = ((blockIdx.x & 7) << 6) + (blockIdx.x >> 3);
  const int qt = wgid & 15, h = (wgid >> 4) & 15, b = wgid >> 8;
  const size_t bh = (size_t)(b * 16 + h) << 18;
  const u16* Qb = Q + bh;
  const u16* Kb = Kt + bh;
  const u16* Vb = VT + bh;
  u16* Pw = &Pb[w][0];

  const int qr0 = (qt << 7) + (w << 5);
  bf16x8 qf[2][4];
#pragma unroll
  for (int mi = 0; mi < 2; mi++)
#pragma unroll
    for (int kk = 0; kk < 4; kk++)
      qf[mi][kk] = *(const bf16x8*)(Qb + ((size_t)(qr0 + (mi << 4) + lr) << 7) + (kk << 5) + (g << 3));

  // staging lane constants
  const int krow_l = lane >> 4;            // 0..3 within 4-row group
  const int kcg_base = lane & 15;
  const int vrow_l = lane >> 3;            // 0..7 within 8-row group
  const int vcg_base = lane & 7;

  auto stageK = [&](int kt) {
#pragma unroll
    for (int i = 0; i < 4; i++) {
      const int grp = (w << 2) + i;                  // 0..15
      const int row = (grp << 2) + krow_l;           // 0..63
      const int cg = kcg_base ^ (row & 7);
      async16(Kb + ((size_t)((kt << 6) + row) << 7) + (cg << 3), Ks + (grp << 9));
    }
  };
  auto stageV = [&](int kt) {
#pragma unroll
    for (int i = 0; i < 4; i++) {
      const int grp = (w << 2) + i;                  // 0..15
      const int d = (grp << 3) + vrow_l;             // 0..127
      const int cg = vcg_base ^ (d & 7);
      async16(Vb + ((size_t)d << 11) + (kt << 6) + (cg << 3), Vs + (grp << 9));
    }
  };

  const f32x4 zf = {0.f, 0.f, 0.f, 0.f};
  f32x4 o[2][8];
  float m_[2][4], l_[2][4];
#pragma unroll
  for (int mi = 0; mi < 2; mi++) {
#pragma unroll
    for (int ni = 0; ni < 8; ni++) o[mi][ni] = zf;
#pragma unroll
    for (int e = 0; e < 4; e++) { m_[mi][e] = -1.0e30f; l_[mi][e] = 0.f; }
  }

  stageK(0);
  stageV(0);
  __syncthreads();

  for (int kt = 0; kt < 32; kt++) {
    // ---- S = Q K^T (reads Ks) ----
    f32x4 s[2][4];
#pragma unroll
    for (int mi = 0; mi < 2; mi++)
#pragma unroll
      for (int ni = 0; ni < 4; ni++) s[mi][ni] = zf;
#pragma unroll
    for (int kk = 0; kk < 4; kk++) {
      bf16x8 kf[4];
#pragma unroll
      for (int ni = 0; ni < 4; ni++) {
        const int row = (ni << 4) + lr;
        kf[ni] = ldsv(Ks + (row << 7) + ((((kk << 2) + g) ^ (row & 7)) << 3));
      }
      __builtin_amdgcn_s_setprio(1);
#pragma unroll
      for (int mi = 0; mi < 2; mi++)
#pragma unroll
        for (int ni = 0; ni < 4; ni++)
          s[mi][ni] = __builtin_amdgcn_mfma_f32_16x16x32_bf16(qf[mi][kk], kf[ni], s[mi][ni], 0, 0, 0);
      __builtin_amdgcn_s_setprio(0);
    }

    // ---- online softmax (base-2; scores pre-scaled by log2e) ----
    float pm[2][4];
#pragma unroll
    for (int mi = 0; mi < 2; mi++)
#pragma unroll
      for (int e = 0; e < 4; e++) {
        float v = fmaxf(fmaxf(s[mi][0][e], s[mi][1][e]), fmaxf(s[mi][2][e], s[mi][3][e]));
        v = fmaxf(v, __shfl_xor(v, 1));
        v = fmaxf(v, __shfl_xor(v, 2));
        v = fmaxf(v, __shfl_xor(v, 4));
        v = fmaxf(v, __shfl_xor(v, 8));
        pm[mi][e] = v;
      }
    bool need = false;
#pragma unroll
    for (int mi = 0; mi < 2; mi++)
#pragma unroll
      for (int e = 0; e < 4; e++) need = need || (pm[mi][e] > m_[mi][e] + 8.0f);
    if (__any(need)) {
      float al[2][4];
#pragma unroll
      for (int mi = 0; mi < 2; mi++)
#pragma unroll
        for (int e = 0; e < 4; e++) {
          const float mn = fmaxf(m_[mi][e], pm[mi][e]);
          const float a = EXP2(m_[mi][e] - mn);
          m_[mi][e] = mn;
          l_[mi][e] *= a;
          al[mi][e] = a;
        }
#pragma unroll
      for (int mi = 0; mi < 2; mi++)
#pragma unroll
        for (int ni = 0; ni < 8; ni++)
#pragma unroll
          for (int e = 0; e < 4; e++) o[mi][ni][e] *= al[mi][e];
    }
    float ps[2][4];
#pragma unroll
    for (int mi = 0; mi < 2; mi++)
#pragma unroll
      for (int e = 0; e < 4; e++) ps[mi][e] = 0.f;
#pragma unroll
    for (int mi = 0; mi < 2; mi++)
#pragma unroll
      for (int ni = 0; ni < 4; ni++)
#pragma unroll
        for (int e = 0; e < 4; e++) {
          const float p = EXP2(s[mi][ni][e] - m_[mi][e]);
          s[mi][ni][e] = p;
          ps[mi][e] += p;
        }
#pragma unroll
    for (int mi = 0; mi < 2; mi++)
#pragma unroll
      for (int e = 0; e < 4; e++) {
        float t = ps[mi][e];
        t += __shfl_xor(t, 1);
        t += __shfl_xor(t, 2);
        t += __shfl_xor(t, 4);
        t += __shfl_xor(t, 8);
        l_[mi][e] += t;
      }
    // P -> per-wave LDS bf16 (swizzled rows)
#pragma unroll
    for (int mi = 0; mi < 2; mi++)
#pragma unroll
      for (int ni = 0; ni < 4; ni++)
#pragma unroll
        for (int e = 0; e < 4; e++) {
          const int row = (mi << 4) + (g << 2) + e;
          const int col = (ni << 4) + lr;
          Pw[(row << 6) + (((col >> 3) ^ (row & 7)) << 3) + (col & 7)] = f2b(s[mi][ni][e]);
        }

    __syncthreads();               // B1: Ks reads done; V(kt) resident
    if (kt < 31) stageK(kt + 1);   // drains under PV at B2

    // ---- O += P V (reads Vs, Pw) ----
#pragma unroll
    for (int kk = 0; kk < 2; kk++) {
      bf16x8 pf[2];
#pragma unroll
      for (int mi = 0; mi < 2; mi++) {
        const int row = (mi << 4) + lr;
        pf[mi] = ldsv(Pw + (row << 6) + ((((kk << 2) + g) ^ (row & 7)) << 3));
      }
      bf16x8 vf[8];
#pragma unroll
      for (int ni = 0; ni < 8; ni++) {
        const int d = (ni << 4) + lr;
        vf[ni] = ldsv(Vs + (d << 6) + ((((kk << 2) + g) ^ (d & 7)) << 3));
      }
      __builtin_amdgcn_s_setprio(1);
#pragma unroll
      for (int mi = 0; mi < 2; mi++)
#pragma unroll
        for (int ni = 0; ni < 8; ni++)
          o[mi][ni] = __builtin_amdgcn_mfma_f32_16x16x32_bf16(pf[mi], vf[ni], o[mi][ni], 0, 0, 0);
      __builtin_amdgcn_s_setprio(0);
    }

    __syncthreads();               // B2: Vs reads done; K(kt+1) drained
    if (kt < 31) stageV(kt + 1);   // drains under next QK^T+softmax at B1
  }

  // ---- epilogue: O/l -> Og bf16 [B*N][2048]
  u16* Ob = Og + ((size_t)b << 22) + (h << 7);
#pragma unroll
  for (int mi = 0; mi < 2; mi++) {
    float inv[4];
#pragma unroll
    for (int e = 0; e < 4; e++) inv[e] = 1.0f / l_[mi][e];
#pragma unroll
    for (int ni = 0; ni < 8; ni++) {
      const int d = (ni << 4) + lr;
#pragma unroll
      for (int e = 0; e < 4; e++) {
        const int n = qr0 + (mi << 4) + (g << 2) + e;
        Ob[((size_t)n << 11) + d] = f2b(o[mi][ni][e] * inv[e]);
      }
    }
  }
}

// ---------------------------------------------------------------------------
extern "C" void kernel_launch(void* const* d_in, const int* in_sizes, int n_in,
                              void* d_out, int out_size, void* d_ws, size_t ws_size,
                              hipStream_t stream) {
  const float* x = (const float*)d_in[0];
  const float* rope = (const float*)d_in[1];
  const float* qkv_w = (const float*)d_in[2];
  const float* out_w = (const float*)d_in[3];
  float* out = (float*)d_out;

  char* ws = (char*)d_ws;
  u16* xb    = (u16*)(ws);                 // 16,777,216 B ; reused as Og
  u16* wqkvT = (u16*)(ws + 16777216);      // 25,165,824 B
  u16* woT   = (u16*)(ws + 41943040);      //  8,388,608 B
  u16* Qp    = (u16*)(ws + 50331648);      // 16,777,216 B
  u16* Kp    = (u16*)(ws + 67108864);      // 16,777,216 B
  u16* VTp   = (u16*)(ws + 83886080);      // 16,777,216 B
  u16* Og    = xb;                          // alias: xb dead after gemm1

  // x (2*2048*2048 fp32) -> bf16
  k_cvt<<<8192, 256, 0, stream>>>(x, xb, 2097152);
  // qkv_w [2048][6144] -> [6144][2048] bf16 ; out_w [2048][2048] -> T bf16
  k_tcvt<<<dim3(192, 64), dim3(32, 8), 0, stream>>>(qkv_w, wqkvT, 2048, 6144);
  k_tcvt<<<dim3(64, 64), dim3(32, 8), 0, stream>>>(out_w, woT, 2048, 2048);
  // qkv projection + RoPE + scatter to Q/K/VT
  k_gemm<1><<<dim3(48, 32), 256, 0, stream>>>(xb, wqkvT, 2048, nullptr, 0, rope, Qp, Kp, VTp);
  // flash attention (1-D grid for XCD swizzle; 512 blocks)
  k_attn<<<512, 256, 0, stream>>>(Qp, Kp, VTp, Og);
  // output projection -> fp32 d_out
  k_gemm<0><<<dim3(16, 32), 256, 0, stream>>>(Og, woT, 2048, out, 2048, nullptr, nullptr, nullptr, nullptr);
}